// Round 7
// baseline (115.630 us; speedup 1.0000x reference)
//
#include <hip/hip_runtime.h>

typedef int v4i __attribute__((ext_vector_type(4)));

#define NIMG 32
#define CIN  256
#define COUT 256
#define HW   3136   // 56*56
#define W56  56
#define HP   58     // padded H/W
#define PIMG (HP * HP)                       // 3364
#define XQP_BYTES (NIMG * PIMG * CIN)        // 27,557,888
#define WP_BYTES  (9 * COUT * CIN)           // 589,824

#define BARRIER() asm volatile("s_barrier" ::: "memory")
#define VMCNT(n)  asm volatile("s_waitcnt vmcnt(" #n ")" ::: "memory")

// ---------------------------------------------------------------------------
// Kernel 0: zero only the pad border (228 px/image * 256B)
// ---------------------------------------------------------------------------
__global__ __launch_bounds__(256) void zero_border(v4i* __restrict__ p)
{
    int i = blockIdx.x * 256 + threadIdx.x;
    if (i >= NIMG * 228 * 16) return;
    int n = i / 3648, r = i % 3648, pix = r >> 4, c = r & 15;
    int h, w;
    if (pix < 58)       { h = 0;         w = pix;       }
    else if (pix < 116) { h = 57;        w = pix - 58;  }
    else if (pix < 172) { h = pix - 115; w = 0;         }
    else                { h = pix - 171; w = 57;        }
    v4i z = {0, 0, 0, 0};
    p[(size_t)(n * PIMG + h * HP + w) * 16 + c] = z;
}

// ---------------------------------------------------------------------------
// Kernel 1: quantize + transpose  NCHW f32 -> padded NHWC int8 (interior)
// ---------------------------------------------------------------------------
__global__ __launch_bounds__(256) void quantize_pad(
    const float* __restrict__ x, signed char* __restrict__ xqp)
{
    __shared__ int tile[64][65];
    const int n  = blockIdx.z;
    const int c0 = blockIdx.y * 64;
    const int p0 = blockIdx.x * 64;
    const int tid = threadIdx.x;

    const int px   = tid & 63;
    const int crow = tid >> 6;
    const float* xb = x + ((size_t)(n * CIN + c0)) * HW + p0;
#pragma unroll
    for (int i = 0; i < 16; ++i) {
        int c = crow + i * 4;
        float v = xb[(size_t)c * HW + px];
        v = fminf(fmaxf(v, -1.f), 1.f);
        tile[c][px] = (int)rintf(v * 127.f);
    }
    __syncthreads();

    const int c4   = tid & 15;
    const int prow = tid >> 4;
#pragma unroll
    for (int i = 0; i < 4; ++i) {
        int p  = prow + i * 16;
        int hw = p0 + p;
        int oh = hw / W56, ow = hw % W56;
        int b0 = tile[c4 * 4 + 0][p] & 255;
        int b1 = tile[c4 * 4 + 1][p] & 255;
        int b2 = tile[c4 * 4 + 2][p] & 255;
        int b3 = tile[c4 * 4 + 3][p] & 255;
        int packed = b0 | (b1 << 8) | (b2 << 16) | (b3 << 24);
        *(int*)(xqp + ((size_t)(n * PIMG + (oh + 1) * HP + (ow + 1))) * CIN
                    + c0 + c4 * 4) = packed;
    }
}

// ---------------------------------------------------------------------------
// Kernel 2: weight repack  OIHW int32{-1,0,1} -> [step 0..35][cout 256][64B]
// ---------------------------------------------------------------------------
__global__ __launch_bounds__(256) void repack_w(
    const int* __restrict__ wq, signed char* __restrict__ wp2)
{
    int idx  = blockIdx.x * 256 + threadIdx.x;   // < 589824
    int t    = idx >> 16;
    int rem  = idx & 65535;
    int kc   = rem >> 14;
    int rem2 = rem & 16383;
    int co   = rem2 >> 6;
    int c6   = rem2 & 63;
    int ci   = kc * 64 + c6;
    wp2[idx] = (signed char)wq[(co * CIN + ci) * 9 + t];
}

// ---------------------------------------------------------------------------
// Kernel 3: implicit-GEMM conv, A (weights) direct global->VGPR (L2-resident,
// register double-buffer), B (activations) via 4-deep LDS ring (32KB).
// Block 128 cout x 128 px, 4 waves (2x2) of 64x64, one barrier per step,
// counted VMCNT(8). LDS/step = 24KB (214cy) << MFMA 326cy -> MFMA-bound.
// ---------------------------------------------------------------------------
__device__ __forceinline__ void gll16(const void* g, void* l)
{
    __builtin_amdgcn_global_load_lds(
        (const __attribute__((address_space(1))) int*)g,
        (__attribute__((address_space(3))) int*)l, 16, 0, 0);
}

__global__ __launch_bounds__(256) void bitconv_mfma(
    const signed char* __restrict__ xqp, const signed char* __restrict__ wp2,
    const float* __restrict__ s_, const float* __restrict__ bias,
    const float* __restrict__ act_s_p, float* __restrict__ out)
{
    __shared__ signed char Bs[4][8192];   // 4-deep ring, 128 px x 64B each

    const int tid  = threadIdx.x;
    const int lane = tid & 63;
    const int wid  = tid >> 6;          // 0..3
    const int wr   = wid >> 1;          // cout half
    const int wc   = wid & 1;           // px half
    const int l15  = lane & 15;
    const int kg   = lane >> 4;
    const int kgs  = ((kg ^ ((l15 >> 1) & 3)) << 4);   // swizzled B chunk

    // XCD-bijective swizzle (1568 % 8 == 0)
    const int b  = blockIdx.x;
    const int w  = (b & 7) * 196 + (b >> 3);
    const int px0   = (w >> 1) * 128;
    const int cout0 = (w & 1) * 128;

    // ---- B staging addresses (swizzle baked into the global source) ----
    const int srow   = tid >> 2;                         // 0..63
    const int schunk = (((tid & 3) ^ ((tid >> 3) & 3)) << 4);
    const signed char* bsrc[2];
#pragma unroll
    for (int r = 0; r < 2; ++r) {
        int p = px0 + srow + r * 64;
        int n = p / HW, q = p % HW;
        bsrc[r] = xqp
            + ((size_t)(n * PIMG + (q / W56 + 1) * HP + (q % W56 + 1))) * CIN
            + schunk;
    }

    // ---- A per-lane global fragment base (unswizzled; straight from L2) ----
    const signed char* ap = wp2 + (cout0 + wr * 64 + l15) * 64 + kg * 16;
    // fragment i at +i*1024, step s at +s*16384

    // ---- B fragment ds_read offsets (swizzled) ----
    int boff[4];
#pragma unroll
    for (int j = 0; j < 4; ++j)
        boff[j] = (wc * 64 + j * 16 + l15) * 64 + kgs;

    v4i acc[4][4] = {};
    v4i a_cur[4], a_nxt[4];

    const int wb = wid * 1024;          // wave-uniform LDS sub-base

    auto stageB = [&](int buf, int s) {
        int t9 = s >> 2, kc = s & 3;
        int bo = ((t9 / 3 - 1) * HP + (t9 % 3 - 1)) * CIN + kc * 64;
        signed char* L = &Bs[buf][0];
        gll16(bsrc[0] + bo, L + wb);
        gll16(bsrc[1] + bo, L + 4096 + wb);
    };

    // prologue: B0,B1 staged; A0 loaded
    stageB(0, 0);
    stageB(1, 1);
#pragma unroll
    for (int i = 0; i < 4; ++i)
        a_cur[i] = *(const v4i*)(ap + i * 1024);

    for (int s = 0; s < 36; ++s) {
        // issue next A (regs) and B(s+2) (LDS ring, distance 2 = safe WAR)
        if (s < 35) {
            const signed char* a = ap + (s + 1) * 16384;
#pragma unroll
            for (int i = 0; i < 4; ++i)
                a_nxt[i] = *(const v4i*)(a + i * 1024);
        }
        if (s < 34) stageB((s + 2) & 3, s + 2);

        // counted wait: drain A(s) + B(s); keep newer prefetches in flight
        if (s == 0)       { VMCNT(6); }
        else if (s <= 33) { VMCNT(8); }
        else if (s == 34) { VMCNT(6); }
        else              { VMCNT(0); }
        BARRIER();

        const signed char* L = &Bs[s & 3][0];
        v4i bb[4];
#pragma unroll
        for (int j = 0; j < 4; ++j) bb[j] = *(const v4i*)(L + boff[j]);

        __builtin_amdgcn_s_setprio(1);
#pragma unroll
        for (int i = 0; i < 4; ++i)
#pragma unroll
            for (int j = 0; j < 4; ++j)
                acc[i][j] = __builtin_amdgcn_mfma_i32_16x16x64_i8(
                    a_cur[i], bb[j], acc[i][j], 0, 0, 0);
        __builtin_amdgcn_s_setprio(0);

#pragma unroll
        for (int i = 0; i < 4; ++i) a_cur[i] = a_nxt[i];
    }

    // ---- epilogue: y = acc * (act_s * s[c]) + bias[c], NCHW f32 ----
    const float a_s = act_s_p[0];
    int nn[4], hh[4];
#pragma unroll
    for (int j = 0; j < 4; ++j) {
        int op = px0 + wc * 64 + j * 16 + l15;
        nn[j] = op / HW;
        hh[j] = op % HW;
    }
#pragma unroll
    for (int i = 0; i < 4; ++i) {
        int cb = cout0 + wr * 64 + i * 16 + kg * 4;
        float sc[4], bi[4];
#pragma unroll
        for (int r = 0; r < 4; ++r) {
            sc[r] = a_s * s_[cb + r];
            bi[r] = bias[cb + r];
        }
#pragma unroll
        for (int j = 0; j < 4; ++j)
#pragma unroll
            for (int r = 0; r < 4; ++r)
                out[((size_t)(nn[j] * COUT + cb + r)) * HW + hh[j]] =
                    (float)acc[i][j][r] * sc[r] + bi[r];
    }
}

// ---------------------------------------------------------------------------
extern "C" void kernel_launch(void* const* d_in, const int* in_sizes, int n_in,
                              void* d_out, int out_size, void* d_ws, size_t ws_size,
                              hipStream_t stream)
{
    const float* x     = (const float*)d_in[0];
    const int*   w_q   = (const int*)d_in[1];
    const float* s     = (const float*)d_in[2];
    const float* bias  = (const float*)d_in[3];
    const float* act_s = (const float*)d_in[4];

    signed char* xqp = (signed char*)d_ws;
    signed char* wp2 = (signed char*)d_ws + XQP_BYTES;

    zero_border<<<(NIMG * 228 * 16 + 255) / 256, 256, 0, stream>>>((v4i*)xqp);
    quantize_pad<<<dim3(49, 4, NIMG), 256, 0, stream>>>(x, xqp);
    repack_w<<<dim3(WP_BYTES / 256), 256, 0, stream>>>(w_q, wp2);
    bitconv_mfma<<<dim3(1568), 256, 0, stream>>>(
        xqp, wp2, s, bias, act_s, (float*)d_out);
}

// Round 8
// 102.918 us; speedup vs baseline: 1.1235x; 1.1235x over previous
//
#include <hip/hip_runtime.h>

typedef int v4i __attribute__((ext_vector_type(4)));

#define NIMG 32
#define CIN  256
#define COUT 256
#define HW   3136   // 56*56
#define W56  56
#define HP   58     // padded H/W
#define PIMG (HP * HP)                       // 3364
#define XQP_BYTES (NIMG * PIMG * CIN)        // 27,557,888
#define WP_BYTES  (9 * COUT * CIN)           // 589,824

#define BARRIER() asm volatile("s_barrier" ::: "memory")
#define VMCNT(n)  asm volatile("s_waitcnt vmcnt(" #n ")" ::: "memory")

// ---------------------------------------------------------------------------
// Kernel 0: zero only the pad border (228 px/image * 256B)
// ---------------------------------------------------------------------------
__global__ __launch_bounds__(256) void zero_border(v4i* __restrict__ p)
{
    int i = blockIdx.x * 256 + threadIdx.x;
    if (i >= NIMG * 228 * 16) return;
    int n = i / 3648, r = i % 3648, pix = r >> 4, c = r & 15;
    int h, w;
    if (pix < 58)       { h = 0;         w = pix;       }
    else if (pix < 116) { h = 57;        w = pix - 58;  }
    else if (pix < 172) { h = pix - 115; w = 0;         }
    else                { h = pix - 171; w = 57;        }
    v4i z = {0, 0, 0, 0};
    p[(size_t)(n * PIMG + h * HP + w) * 16 + c] = z;
}

// ---------------------------------------------------------------------------
// Kernel 1: quantize + transpose  NCHW f32 -> padded NHWC int8 (interior)
// ---------------------------------------------------------------------------
__global__ __launch_bounds__(256) void quantize_pad(
    const float* __restrict__ x, signed char* __restrict__ xqp)
{
    __shared__ int tile[64][65];
    const int n  = blockIdx.z;
    const int c0 = blockIdx.y * 64;
    const int p0 = blockIdx.x * 64;
    const int tid = threadIdx.x;

    const int px   = tid & 63;
    const int crow = tid >> 6;
    const float* xb = x + ((size_t)(n * CIN + c0)) * HW + p0;
#pragma unroll
    for (int i = 0; i < 16; ++i) {
        int c = crow + i * 4;
        float v = xb[(size_t)c * HW + px];
        v = fminf(fmaxf(v, -1.f), 1.f);
        tile[c][px] = (int)rintf(v * 127.f);
    }
    __syncthreads();

    const int c4   = tid & 15;
    const int prow = tid >> 4;
#pragma unroll
    for (int i = 0; i < 4; ++i) {
        int p  = prow + i * 16;
        int hw = p0 + p;
        int oh = hw / W56, ow = hw % W56;
        int b0 = tile[c4 * 4 + 0][p] & 255;
        int b1 = tile[c4 * 4 + 1][p] & 255;
        int b2 = tile[c4 * 4 + 2][p] & 255;
        int b3 = tile[c4 * 4 + 3][p] & 255;
        int packed = b0 | (b1 << 8) | (b2 << 16) | (b3 << 24);
        *(int*)(xqp + ((size_t)(n * PIMG + (oh + 1) * HP + (ow + 1))) * CIN
                    + c0 + c4 * 4) = packed;
    }
}

// ---------------------------------------------------------------------------
// Kernel 2: weight repack  OIHW int32{-1,0,1} -> [step 0..35][cout 256][64B]
// ---------------------------------------------------------------------------
__global__ __launch_bounds__(256) void repack_w(
    const int* __restrict__ wq, signed char* __restrict__ wp2)
{
    int idx  = blockIdx.x * 256 + threadIdx.x;   // < 589824
    int t    = idx >> 16;
    int rem  = idx & 65535;
    int kc   = rem >> 14;
    int rem2 = rem & 16383;
    int co   = rem2 >> 6;
    int c6   = rem2 & 63;
    int ci   = kc * 64 + c6;
    wp2[idx] = (signed char)wq[(co * CIN + ci) * 9 + t];
}

// ---------------------------------------------------------------------------
// Kernel 3: m201-geometry phased implicit-GEMM conv.
// Block 256 cout x 256 px, BK=64, 8 waves (2Mx4N), per-wave 128x64
// (12 ds_read : 32 MFMA). Two double-barrier phases per K-step:
//   {8 reads | 2 gll16 | barrier | 16 MFMA | barrier}
//   {4 reads | 2 gll16 | barrier | 16 MFMA | vmcnt | barrier}
// 3-deep LDS ring (96KB, 1 block/CU), counted VMCNT(4), setprio, XCD swizzle.
// ---------------------------------------------------------------------------
__device__ __forceinline__ void gll16(const void* g, void* l)
{
    __builtin_amdgcn_global_load_lds(
        (const __attribute__((address_space(1))) int*)g,
        (__attribute__((address_space(3))) int*)l, 16, 0, 0);
}

__global__ __launch_bounds__(512) void bitconv_mfma(
    const signed char* __restrict__ xqp, const signed char* __restrict__ wp2,
    const float* __restrict__ s_, const float* __restrict__ bias,
    const float* __restrict__ act_s_p, float* __restrict__ out)
{
    // per buffer: A 16KB (256 cout x 64B) + B 16KB (256 px x 64B)
    __shared__ signed char lds[3][32768];

    const int tid  = threadIdx.x;
    const int lane = tid & 63;
    const int wid  = tid >> 6;          // 0..7
    const int wr   = wid >> 2;          // 0..1  cout half (128 each)
    const int wc   = wid & 3;           // 0..3  px quarter (64 each)
    const int l15  = lane & 15;
    const int kg   = lane >> 4;
    const int kgs  = ((kg ^ ((l15 >> 1) & 3)) << 4);   // swizzled chunk

    // XCD-bijective swizzle (392 % 8 == 0)
    const int b   = blockIdx.x;
    const int px0 = ((b & 7) * 49 + (b >> 3)) * 256;

    // ---- staging addresses (swizzle baked into the global source) ----
    const int srow   = tid >> 2;                         // 0..127
    const int schunk = (((tid & 3) ^ ((tid >> 3) & 3)) << 4);
    const signed char* asrc = wp2 + srow * 64 + schunk;  // +k*8192, +s*16384

    const signed char* bsrc[2];
#pragma unroll
    for (int r = 0; r < 2; ++r) {
        int p = px0 + srow + r * 128;
        int n = p / HW, q = p % HW;
        bsrc[r] = xqp
            + ((size_t)(n * PIMG + (q / W56 + 1) * HP + (q % W56 + 1))) * CIN
            + schunk;
    }

    // ---- fragment ds_read offsets (swizzled) ----
    int aoff[8], boff[4];
#pragma unroll
    for (int i = 0; i < 8; ++i)
        aoff[i] = (wr * 128 + i * 16 + l15) * 64 + kgs;
#pragma unroll
    for (int j = 0; j < 4; ++j)
        boff[j] = 16384 + (wc * 64 + j * 16 + l15) * 64 + kgs;

    v4i acc[8][4] = {};

    const int wb = wid * 1024;          // wave-uniform LDS sub-base

    auto stageA = [&](int buf, int s) { // 2 gll16: A 16KB (256 rows)
        signed char* L = &lds[buf][0];
        const signed char* a = asrc + s * 16384;
        gll16(a,        L + wb);
        gll16(a + 8192, L + 8192 + wb);
    };
    auto stageB = [&](int buf, int s) { // 2 gll16: B 16KB (256 px)
        int t9 = s >> 2, kc = s & 3;
        int bo = ((t9 / 3 - 1) * HP + (t9 % 3 - 1)) * CIN + kc * 64;
        signed char* L = &lds[buf][0];
        gll16(bsrc[0] + bo, L + 16384 + wb);
        gll16(bsrc[1] + bo, L + 24576 + wb);
    };

    // prologue: steps 0,1 staged; wait step 0's 4 loads (4 stay in flight)
    stageA(0, 0); stageB(0, 0);
    stageA(1, 1); stageB(1, 1);
    VMCNT(4);
    BARRIER();

    for (int it = 0; it < 12; ++it) {
#pragma unroll
        for (int u = 0; u < 3; ++u) {
            const int s = it * 3 + u;
            const int nb = (u + 2) % 3;     // buffer being staged (s+2)
            const signed char* L = &lds[u][0];

            // ---- phase 0: read B subtile + A-lo, stage next A ----
            v4i a[4], bb[4];
#pragma unroll
            for (int j = 0; j < 4; ++j) bb[j] = *(const v4i*)(L + boff[j]);
#pragma unroll
            for (int i = 0; i < 4; ++i) a[i]  = *(const v4i*)(L + aoff[i]);

            if (s <= 33) stageA(nb, s + 2);

            BARRIER();
            __builtin_amdgcn_s_setprio(1);
#pragma unroll
            for (int i = 0; i < 4; ++i)
#pragma unroll
                for (int j = 0; j < 4; ++j)
                    acc[i][j] = __builtin_amdgcn_mfma_i32_16x16x64_i8(
                        a[i], bb[j], acc[i][j], 0, 0, 0);
            __builtin_amdgcn_s_setprio(0);
            BARRIER();

            // ---- phase 1: read A-hi, stage next B ----
            v4i a2[4];
#pragma unroll
            for (int i = 0; i < 4; ++i) a2[i] = *(const v4i*)(L + aoff[4 + i]);

            if (s <= 33) stageB(nb, s + 2);

            BARRIER();
            __builtin_amdgcn_s_setprio(1);
#pragma unroll
            for (int i = 0; i < 4; ++i)
#pragma unroll
                for (int j = 0; j < 4; ++j)
                    acc[4 + i][j] = __builtin_amdgcn_mfma_i32_16x16x64_i8(
                        a2[i], bb[j], acc[4 + i][j], 0, 0, 0);
            __builtin_amdgcn_s_setprio(0);

            // counted vmcnt: s+1's 4 loads done, s+2's 4 stay in flight
            if (s <= 33)      { VMCNT(4); }
            else if (s == 34) { VMCNT(0); }
            if (s < 35) BARRIER();
        }
    }

    // ---- epilogue: y = acc * (act_s * s[c]) + bias[c], NCHW f32 ----
    const float a_s = act_s_p[0];
    int nn[4], hh[4];
#pragma unroll
    for (int j = 0; j < 4; ++j) {
        int op = px0 + wc * 64 + j * 16 + l15;
        nn[j] = op / HW;
        hh[j] = op % HW;
    }
#pragma unroll
    for (int i = 0; i < 8; ++i) {
        int cb = wr * 128 + i * 16 + kg * 4;
        float sc[4], bi[4];
#pragma unroll
        for (int r = 0; r < 4; ++r) {
            sc[r] = a_s * s_[cb + r];
            bi[r] = bias[cb + r];
        }
#pragma unroll
        for (int j = 0; j < 4; ++j)
#pragma unroll
            for (int r = 0; r < 4; ++r)
                out[((size_t)(nn[j] * COUT + cb + r)) * HW + hh[j]] =
                    (float)acc[i][j][r] * sc[r] + bi[r];
    }
}

// ---------------------------------------------------------------------------
extern "C" void kernel_launch(void* const* d_in, const int* in_sizes, int n_in,
                              void* d_out, int out_size, void* d_ws, size_t ws_size,
                              hipStream_t stream)
{
    const float* x     = (const float*)d_in[0];
    const int*   w_q   = (const int*)d_in[1];
    const float* s     = (const float*)d_in[2];
    const float* bias  = (const float*)d_in[3];
    const float* act_s = (const float*)d_in[4];

    signed char* xqp = (signed char*)d_ws;
    signed char* wp2 = (signed char*)d_ws + XQP_BYTES;

    zero_border<<<(NIMG * 228 * 16 + 255) / 256, 256, 0, stream>>>((v4i*)xqp);
    quantize_pad<<<dim3(49, 4, NIMG), 256, 0, stream>>>(x, xqp);
    repack_w<<<dim3(WP_BYTES / 256), 256, 0, stream>>>(w_q, wp2);
    bitconv_mfma<<<dim3(392), 512, 0, stream>>>(
        xqp, wp2, s, bias, act_s, (float*)d_out);
}